// Round 5
// baseline (234.024 us; speedup 1.0000x reference)
//
#include <hip/hip_runtime.h>
#include <math.h>

// Problem sizes (fixed by reference)
#define Bq 1024
#define Nn 128
#define Mm 8192
#define Ss 256

typedef _Float16 f16;
typedef _Float16 f16x8 __attribute__((ext_vector_type(8)));
typedef _Float16 f16x4 __attribute__((ext_vector_type(4)));
typedef float f32x4 __attribute__((ext_vector_type(4)));

#define PI_F 3.14159265358979323846f
#define INV_SQRT_PI 0.5641895835477563f
#define TINY_F 1.17549435e-38f
#define EPS_TOTAL 1e-3f
#define WSC 1024.0f   // w scaling so f16 w stays out of subnormals

// async global->LDS copy, 16B per lane; LDS dest = wave-uniform base + lane*16
#define GLOAD16(g, l) \
    __builtin_amdgcn_global_load_lds((const __attribute__((address_space(1))) void*)(g), \
                                     (__attribute__((address_space(3))) void*)(l), 16, 0, 0)

// ---------------- fused prep+pack: 4 block ranges ----------------
// [0,n0): b-side (|z|^2 + frag-native A pack). n0=256 on chunk 0 else 0.
// [n0,n0+n1): m-side cm constants. n1=2048 on chunk 0 else 0.
// [n0+n1, +n2): pack Bp chunk (frag-native, raw dj/zj with sign).
// [n0+n1+n2, +n3): pack Tt chunk (transposed, via LDS).
__global__ void cpsf_prep_pack(
    const float* __restrict__ z_re, const float* __restrict__ z_im,
    const float* __restrict__ d_re, const float* __restrict__ d_im,
    const float* __restrict__ zj_re, const float* __restrict__ zj_im,
    const float* __restrict__ dj_re, const float* __restrict__ dj_im,
    const float* __restrict__ T_re, const float* __restrict__ T_im,
    const float* __restrict__ alpha, const float* __restrict__ sp_,
    const float* __restrict__ sq_, float* __restrict__ z2,
    float* __restrict__ cm, f16* __restrict__ Az, f16* __restrict__ Bp,
    f16* __restrict__ Tt, int Mc, int m0g, int n0, int n1, int n2, int mshift)
{
    __shared__ float tsm[2 * 64 * 65];
    const int bx = blockIdx.x;
    const int tid = threadIdx.x;
    const int wid = tid >> 6;
    const int l = tid & 63;

    if (bx < n0) {
        // ---- b-side ----
        const int b = bx * 4 + wid;
        const int o = b * Nn;
        float dr0 = d_re[o + l], dr1 = d_re[o + l + 64];
        float di0 = d_im[o + l], di1 = d_im[o + l + 64];
        float zr0 = z_re[o + l], zr1 = z_re[o + l + 64];
        float zi0 = z_im[o + l], zi1 = z_im[o + l + 64];
        float sd = dr0*dr0 + di0*di0 + dr1*dr1 + di1*di1;
        float sz = zr0*zr0 + zi0*zi0 + zr1*zr1 + zi1*zi1;
#pragma unroll
        for (int off = 1; off < 64; off <<= 1) {
            sd += __shfl_xor(sd, off);
            sz += __shfl_xor(sz, off);
        }
        float nd = sqrtf(sd);
        nd = (nd == 0.0f) ? 1.0f : nd;
        float inv = 1.0f / nd;
        if (l == 0) z2[b] = sz;
        int map = l >> 5, c = l & 31;
        int k8 = (c & 15) * 8;
        const float* src = (map == 0) ? ((c < 16) ? z_re : z_im)
                                      : ((c < 16) ? d_re : d_im);
        float s = (map == 0) ? 1.0f : inv;
        float4 v0 = *(const float4*)(src + (size_t)b * Nn + k8);
        float4 v1 = *(const float4*)(src + (size_t)b * Nn + k8 + 4);
        f16x8 ov = {(f16)(v0.x*s), (f16)(v0.y*s), (f16)(v0.z*s), (f16)(v0.w*s),
                    (f16)(v1.x*s), (f16)(v1.y*s), (f16)(v1.z*s), (f16)(v1.w*s)};
        *(f16x8*)(Az + ((size_t)l * 1024 + b) * 8) = ov;
    } else if (bx < n0 + n1) {
        // ---- m-side constants ----
        const int m = (bx - n0) * 4 + wid;
        const int o = m * Nn;
        float dr0 = dj_re[o + l], dr1 = dj_re[o + l + 64];
        float di0 = dj_im[o + l], di1 = dj_im[o + l + 64];
        float zr0 = zj_re[o + l], zr1 = zj_re[o + l + 64];
        float zi0 = zj_im[o + l], zi1 = zj_im[o + l + 64];
        float snd = dr0*dr0 + di0*di0 + dr1*dr1 + di1*di1;
        float sc1 = dr0*zr0 + di0*zi0 + dr1*zr1 + di1*zi1;
        float sc2 = dr0*zi0 - di0*zr0 + dr1*zi1 - di1*zr1;
        float sz2 = zr0*zr0 + zi0*zi0 + zr1*zr1 + zi1*zi1;
#pragma unroll
        for (int off = 1; off < 64; off <<= 1) {
            snd += __shfl_xor(snd, off);
            sc1 += __shfl_xor(sc1, off);
            sc2 += __shfl_xor(sc2, off);
            sz2 += __shfl_xor(sz2, off);
        }
        if (l == 0) {
            float nd = sqrtf(snd);
            nd = (nd == 0.0f) ? 1.0f : nd;
            float inv = 1.0f / nd;
            cm[0*Mm + m] = inv;
            cm[1*Mm + m] = sc1 * inv;
            cm[2*Mm + m] = sc2 * inv;
            cm[3*Mm + m] = sz2;
            float sp = fmaxf(sp_[m], TINY_F);
            float sq = fmaxf(sq_[m], TINY_F);
            float sc = sqrtf(sp / PI_F);
            cm[4*Mm + m] = PI_F / sp;
            cm[5*Mm + m] = PI_F / sq;
            cm[6*Mm + m] = fmaxf(alpha[m], TINY_F) * sc * INV_SQRT_PI;
            cm[7*Mm + m] = sc;
        }
    } else if (bx < n0 + n1 + n2) {
        // ---- pack Bp (frag-native) ----
        int idx = (bx - n0 - n1) * 256 + tid;   // 96*Mc total
        int m = idx & (Mc - 1);
        int pc = idx >> mshift;                 // 0..95
        int p = pc >> 5, c = pc & 31;
        int mg = m0g + m;
        int hi = (c >= 16);
        int k8 = (c & 15) * 8;
        const float* src;
        float sgn = 1.0f;
        if (p == 0)      src = hi ? dj_im : dj_re;
        else if (p == 1) { src = hi ? dj_re : dj_im; sgn = hi ? 1.0f : -1.0f; }
        else             src = hi ? zj_im : zj_re;
        float4 v0 = *(const float4*)(src + (size_t)mg * Nn + k8);
        float4 v1 = *(const float4*)(src + (size_t)mg * Nn + k8 + 4);
        f16x8 o = {(f16)(v0.x*sgn), (f16)(v0.y*sgn), (f16)(v0.z*sgn), (f16)(v0.w*sgn),
                   (f16)(v1.x*sgn), (f16)(v1.y*sgn), (f16)(v1.z*sgn), (f16)(v1.w*sgn)};
        *(f16x8*)(Bp + (size_t)idx * 8) = o;
    } else {
        // ---- pack Tt (transposed) ----
        const int bt = bx - n0 - n1 - n2;
        const int nmb = Mc >> 6;
        const int mb = (bt & (nmb - 1)) * 64, sb = (bt / nmb) * 64;
        float* tr = tsm;
        float* ti = tsm + 64 * 65;
        const int i0 = tid >> 6, jj0 = tid & 63;
#pragma unroll
        for (int it = 0; it < 16; ++it) {
            int i = it * 4 + i0;
            tr[i * 65 + jj0] = T_re[(size_t)(m0g + mb + i) * Ss + sb + jj0];
            ti[i * 65 + jj0] = T_im[(size_t)(m0g + mb + i) * Ss + sb + jj0];
        }
        __syncthreads();
#pragma unroll
        for (int it = 0; it < 16; ++it) {
            int jj = it * 4 + i0;
            int sp = (sb + jj) * 2;
            Tt[(size_t)sp * Mc + mb + jj0]       = (f16)tr[jj0 * 65 + jj];
            Tt[(size_t)(sp + 1) * Mc + mb + jj0] = (f16)ti[jj0 * 65 + jj];
        }
    }
}

// ---------------- MFMA kernel A: A direct-to-reg, B via small LDS dbuf ----------------
// Block 128b x 64m, 4 waves (2x2), wave tile 64b x 32m, K=256 (8 steps of 32).
// A fragments: coalesced global loads from frag-native Az, register double-buffered.
// B: 12KB/step LDS double buffer (2x cross-wave reuse). LDS 24KB -> 6 blocks/CU.
// Counted vmcnt(11) per step (current step drained, next step's 3 B + 8 A in flight),
// raw s_barriers, setprio around MFMA cluster.
__global__ __launch_bounds__(256, 2) void cpsf_gemm_w(
    const f16* __restrict__ Az, const f16* __restrict__ Bp,
    const float* __restrict__ cm, const float* __restrict__ z2v,
    f16* __restrict__ wbuf, float* __restrict__ den, int Mc, int m0g)
{
    __shared__ __align__(16) f16 sm[2 * 768 * 8];    // 24 KB total
    const int tid = threadIdx.x;
    const int wid = tid >> 6;
    const int lane = tid & 63;
    const int q = lane >> 4;
    const int li = lane & 15;

    // XCD-aware swizzle: XCD x owns contiguous 1/8 of m-tiles
    const int nmt = gridDim.x;
    const int sbid = blockIdx.x + nmt * blockIdx.y;
    const int xcd = sbid & 7;
    const int jb = sbid >> 3;
    const int mpg = nmt >> 3;
    const int mtile = xcd * mpg + (jb & (mpg - 1));
    const int btile = jb / mpg;
    const int mb0 = mtile * 64;
    const int bb0 = btile * 128;
    const int wb0 = (wid >> 1) * 64;
    const int wm0 = (wid & 1) * 32;
    const int BUFO = 768 * 8;

    // B staging: 12 slots (g=0..3 k-chunks x p=0..2 maps), 3 per wave
    const f16* gp[3];
    f16* lb[3];
#pragma unroll
    for (int i = 0; i < 3; ++i) {
        int c = i * 4 + wid;                   // 0..11
        int g = c / 3, p = c % 3;
        gp[i] = Bp + ((size_t)(p * 32 + g) * Mc + mb0 + lane) * 8;
        lb[i] = sm + (size_t)(g * 192 + p * 64) * 8;
    }
    const size_t KSB = (size_t)4 * Mc * 8;     // B advance per K-step

    // A direct-load bases (lane (q,li): k-chunk = ks*4+q, b-row = wb0 + t*16 + li)
    const f16* pAz = Az + ((size_t)q * 1024 + bb0 + wb0 + li) * 8;
    const f16* pAu = pAz + (size_t)32 * 1024 * 8;
    const size_t KSA = (size_t)4 * 1024 * 8;   // A advance per K-step

    f32x4 accP[4][2][3];   // maps 0..2 (pr_raw, pi_raw, z.zj)
    f32x4 accQ[4][2][2];   // maps 3..4 (ar_raw, ai_raw)
#pragma unroll
    for (int t = 0; t < 4; ++t)
#pragma unroll
        for (int u = 0; u < 2; ++u) {
#pragma unroll
            for (int p = 0; p < 3; ++p) accP[t][u][p] = (f32x4){0.f,0.f,0.f,0.f};
#pragma unroll
            for (int p = 0; p < 2; ++p) accQ[t][u][p] = (f32x4){0.f,0.f,0.f,0.f};
        }

    f16x8 azR[2][4], auR[2][4];

#define LOADA(P, KS) do {                                                          \
    const size_t oA = (size_t)(KS) * KSA;                                          \
    azR[P][0] = *(const f16x8*)(pAz + oA);       azR[P][1] = *(const f16x8*)(pAz + oA + 128); \
    azR[P][2] = *(const f16x8*)(pAz + oA + 256); azR[P][3] = *(const f16x8*)(pAz + oA + 384); \
    auR[P][0] = *(const f16x8*)(pAu + oA);       auR[P][1] = *(const f16x8*)(pAu + oA + 128); \
    auR[P][2] = *(const f16x8*)(pAu + oA + 256); auR[P][3] = *(const f16x8*)(pAu + oA + 384); \
} while (0)

    // prologue: stage B(0) into buf0, load A(0) into set 0
#pragma unroll
    for (int i = 0; i < 3; ++i) { GLOAD16(gp[i], lb[i]); gp[i] += KSB; }
    LOADA(0, 0);

#pragma unroll
    for (int ks = 0; ks < 8; ++ks) {
        const int p = ks & 1;
        if (ks > 0) {
            __builtin_amdgcn_sched_barrier(0);
            __builtin_amdgcn_s_barrier();              // C1: buf[p^1] reads done
        }
        if (ks < 7) {
#pragma unroll
            for (int i = 0; i < 3; ++i) { GLOAD16(gp[i], lb[i] + (p ^ 1) * BUFO); gp[i] += KSB; }
            if (ks == 0) LOADA(1, 1); else if (ks == 1) LOADA(0, 2);
            else if (ks == 2) LOADA(1, 3); else if (ks == 3) LOADA(0, 4);
            else if (ks == 4) LOADA(1, 5); else if (ks == 5) LOADA(0, 6);
            else LOADA(1, 7);
            asm volatile("s_waitcnt vmcnt(11)" ::: "memory");  // step-ks B+A done; ks+1 in flight
        } else {
            asm volatile("s_waitcnt vmcnt(0)" ::: "memory");
        }
        __builtin_amdgcn_sched_barrier(0);
        __builtin_amdgcn_s_barrier();                  // C2: buf[p] ready on all waves

        const f16* bs = sm + p * BUFO;
        f16x8 bf[3][2];
#pragma unroll
        for (int pp = 0; pp < 3; ++pp)
#pragma unroll
            for (int u = 0; u < 2; ++u)
                bf[pp][u] = *(const f16x8*)(bs + (size_t)(q * 192 + pp * 64 + wm0 + u * 16 + li) * 8);

        __builtin_amdgcn_s_setprio(1);
#pragma unroll
        for (int t = 0; t < 4; ++t)
#pragma unroll
            for (int u = 0; u < 2; ++u) {
#pragma unroll
                for (int pp = 0; pp < 3; ++pp)
                    accP[t][u][pp] = __builtin_amdgcn_mfma_f32_16x16x32_f16(azR[p][t], bf[pp][u], accP[t][u][pp], 0, 0, 0);
#pragma unroll
                for (int pp = 0; pp < 2; ++pp)
                    accQ[t][u][pp] = __builtin_amdgcn_mfma_f32_16x16x32_f16(auR[p][t], bf[pp][u], accQ[t][u][pp], 0, 0, 0);
            }
        __builtin_amdgcn_s_setprio(0);
    }
#undef LOADA

    // ---------------- epilogue (fp32) ----------------
    const float GT[8] = {-2.9306374202572440f, -1.9816567566958429f,
                         -1.1571937124467802f, -0.3811869902073221f,
                          0.3811869902073221f,  1.1571937124467802f,
                          1.9816567566958429f,  2.9306374202572440f};
    const float GW[8] = {1.9960407221136762e-04f, 1.7077983007413475e-02f,
                         2.0780232581489188e-01f, 6.6114701255824129e-01f,
                         6.6114701255824129e-01f, 2.0780232581489188e-01f,
                         1.7077983007413475e-02f, 1.9960407221136762e-04f};

    float iv[2], c1[2], c2[2], zj2[2], isp[2], isq[2], cf[2], scl[2];
#pragma unroll
    for (int u = 0; u < 2; ++u) {
        int mg = m0g + mb0 + wm0 + u * 16 + li;
        iv[u]  = cm[0*Mm + mg];
        c1[u]  = cm[1*Mm + mg];  c2[u]  = cm[2*Mm + mg];
        zj2[u] = cm[3*Mm + mg];  isp[u] = cm[4*Mm + mg];
        isq[u] = cm[5*Mm + mg];  cf[u]  = cm[6*Mm + mg];
        scl[u] = cm[7*Mm + mg];
    }

    float dsum[4][4];
#pragma unroll
    for (int t = 0; t < 4; ++t)
#pragma unroll
        for (int r = 0; r < 4; ++r) dsum[t][r] = 0.f;

#pragma unroll
    for (int t = 0; t < 4; ++t) {
#pragma unroll
        for (int r = 0; r < 4; ++r) {
            const int b = bb0 + wb0 + t * 16 + q * 4 + r;
            const float z2b = z2v[b];
#pragma unroll
            for (int u = 0; u < 2; ++u) {
                float pr = accP[t][u][0][r] * iv[u] - c1[u];
                float pi = accP[t][u][1][r] * iv[u] - c2[u];
                float dz2 = z2b + zj2[u] - 2.0f * accP[t][u][2][r];
                float perp2 = fmaxf(dz2 - pr * pr - pi * pi, 0.0f);
                float base = -(isq[u] * perp2 + isp[u] * pi * pi);
                float rho = 0.0f;
#pragma unroll
                for (int k = 0; k < 8; ++k) {
                    float dd = pr - scl[u] * GT[k];
                    rho = fmaf(GW[k], __expf(base - isp[u] * dd * dd), rho);
                }
                float ar = accQ[t][u][0][r] * iv[u], ai = accQ[t][u][1][r] * iv[u];
                float wv = cf[u] * (ar * ar + ai * ai) * rho;
                dsum[t][r] += wv;
                wbuf[(size_t)b * Mc + mb0 + wm0 + u * 16 + li] = (f16)(wv * WSC);
            }
        }
    }
#pragma unroll
    for (int t = 0; t < 4; ++t)
#pragma unroll
        for (int r = 0; r < 4; ++r) {
            float v = dsum[t][r];
            v += __shfl_xor(v, 1);
            v += __shfl_xor(v, 2);
            v += __shfl_xor(v, 4);
            v += __shfl_xor(v, 8);
            if (li == 0) atomicAdd(den + bb0 + wb0 + t * 16 + q * 4 + r, v);
        }
}

// ---------------- MFMA kernel B: osl[z] = w @ Tt^T (split-K slices, NO atomics) ----------------
// Block 128b x 128s', K-window Kw; counted-vmcnt double buffer; plain stores per z-slice.
__global__ __launch_bounds__(256, 3) void cpsf_gemm_out(
    const f16* __restrict__ wbuf, const f16* __restrict__ Tt,
    float* __restrict__ osl, int Mc, int Kw)
{
    __shared__ __align__(16) f16 sm[2 * 1024 * 8];   // 32 KB
    const int tid = threadIdx.x;
    const int wid = tid >> 6;
    const int lane = tid & 63;
    const int q = lane >> 4;
    const int li = lane & 15;
    const int sb0 = blockIdx.x * 128;
    const int bb0 = blockIdx.y * 128;
    const int kz0 = blockIdx.z * Kw;
    float* oz = osl + (size_t)blockIdx.z * ((size_t)Bq * 512);
    const int wb0 = (wid >> 1) * 64;
    const int ws0 = (wid & 1) * 64;
    const int BUFO = 1024 * 8;

    const f16* gp[4];
    f16* lb[4];
#pragma unroll
    for (int i = 0; i < 4; ++i) {
        int c = i * 4 + wid;
        const f16* src;
        if (c < 8) {
            int g = c >> 1, row = (c & 1) * 64 + lane;
            src = wbuf + (size_t)(bb0 + row) * Mc + kz0 + g * 8;
        } else {
            int c2 = c - 8;
            int g = c2 >> 1, row = (c2 & 1) * 64 + lane;
            src = Tt + (size_t)(sb0 + row) * Mc + kz0 + g * 8;
        }
        gp[i] = src;
        lb[i] = sm + (size_t)(i * 256 + wid * 64) * 8;
    }

    f32x4 acc[4][4];
#pragma unroll
    for (int t = 0; t < 4; ++t)
#pragma unroll
        for (int u = 0; u < 4; ++u) acc[t][u] = (f32x4){0.f,0.f,0.f,0.f};

    // prologue: stage step 0
#pragma unroll
    for (int i = 0; i < 4; ++i) { GLOAD16(gp[i], lb[i]); gp[i] += 32; }

    const int nk = Kw >> 5;
    for (int kc = 0; kc < nk; ++kc) {
        const int p = kc & 1;
        if (kc > 0) {
            __builtin_amdgcn_sched_barrier(0);
            __builtin_amdgcn_s_barrier();
        }
        if (kc + 1 < nk) {
#pragma unroll
            for (int i = 0; i < 4; ++i) { GLOAD16(gp[i], lb[i] + (p ^ 1) * BUFO); gp[i] += 32; }
            asm volatile("s_waitcnt vmcnt(4)" ::: "memory");
        } else {
            asm volatile("s_waitcnt vmcnt(0)" ::: "memory");
        }
        __builtin_amdgcn_sched_barrier(0);
        __builtin_amdgcn_s_barrier();

        const f16* bs = sm + p * BUFO;
        f16x8 af[4], bf[4];
#pragma unroll
        for (int t = 0; t < 4; ++t)
            af[t] = *(const f16x8*)(bs + (size_t)(q * 128 + wb0 + t * 16 + li) * 8);
#pragma unroll
        for (int u = 0; u < 4; ++u)
            bf[u] = *(const f16x8*)(bs + (size_t)(512 + q * 128 + ws0 + u * 16 + li) * 8);
        __builtin_amdgcn_s_setprio(1);
#pragma unroll
        for (int t = 0; t < 4; ++t)
#pragma unroll
            for (int u = 0; u < 4; ++u)
                acc[t][u] = __builtin_amdgcn_mfma_f32_16x16x32_f16(af[t], bf[u], acc[t][u], 0, 0, 0);
        __builtin_amdgcn_s_setprio(0);
    }
#pragma unroll
    for (int t = 0; t < 4; ++t)
#pragma unroll
        for (int u = 0; u < 4; ++u)
#pragma unroll
            for (int r = 0; r < 4; ++r)
                oz[(size_t)(bb0 + wb0 + t * 16 + q * 4 + r) * 512 + sb0 + ws0 + u * 16 + li] =
                    acc[t][u][r];
}

// ---------------- finalize: sum Z slices, divide ----------------
__global__ void cpsf_fin(const float* __restrict__ osl, const float* __restrict__ den,
                         float* __restrict__ out, int Z)
{
    int i = blockIdx.x * 256 + threadIdx.x;
    float s = 0.f;
    for (int z = 0; z < Z; ++z) s += osl[(size_t)z * ((size_t)Bq * 512) + i];
    out[i] = s / ((den[i >> 9] + EPS_TOTAL) * WSC);
}

extern "C" void kernel_launch(void* const* d_in, const int* in_sizes, int n_in,
                              void* d_out, int out_size, void* d_ws, size_t ws_size,
                              hipStream_t stream)
{
    (void)in_sizes; (void)n_in; (void)out_size;
    const float* z_re  = (const float*)d_in[0];
    const float* z_im  = (const float*)d_in[1];
    const float* d_re  = (const float*)d_in[2];
    const float* d_im  = (const float*)d_in[3];
    const float* zj_re = (const float*)d_in[4];
    const float* zj_im = (const float*)d_in[5];
    const float* dj_re = (const float*)d_in[6];
    const float* dj_im = (const float*)d_in[7];
    const float* T_re  = (const float*)d_in[8];
    const float* T_im  = (const float*)d_in[9];
    const float* alpha = (const float*)d_in[10];
    const float* s_par = (const float*)d_in[11];
    const float* s_perp= (const float*)d_in[12];

    const size_t SL = (size_t)Bq * 512 * 4;           // 2 MB per slice
    const size_t fixedA = 4096 + 4096 + (size_t)8 * Mm * 4 + (size_t)Bq * 512 * 2;

    // choose total split-K slices Z and chunk size Mc (prefer parallelism, then chunk size)
    int Mc = 0, Z = 0;
    const int Zopt[3] = {16, 8, 4};
    const int Mopt[4] = {8192, 4096, 2048, 1024};
    for (int zi = 0; zi < 3 && !Mc; ++zi)
        for (int mi = 0; mi < 4; ++mi) {
            int Zc = Zopt[zi], Mcc = Mopt[mi];
            int nch = Mm / Mcc;
            if (Zc % nch) continue;
            size_t need = (size_t)Zc * SL + fixedA + (size_t)4608 * Mcc;
            if (need <= ws_size) { Mc = Mcc; Z = Zc; break; }
        }
    if (!Mc) { Mc = 1024; Z = 8; }
    const int nch = Mm / Mc;
    const int zs = Z / nch;
    const int Kw = Mc / zs;
    const int mshift = 31 - __builtin_clz((unsigned)Mc);

    char* w8 = (char*)d_ws;
    const size_t o_sl  = 0;
    const size_t o_den = o_sl + (size_t)Z * SL;
    const size_t o_z2  = o_den + 4096;
    const size_t o_cm  = o_z2 + 4096;
    const size_t o_az  = o_cm + (size_t)8 * Mm * 4;
    const size_t o_ch  = o_az + (size_t)Bq * 512 * 2;

    float* osl = (float*)(w8 + o_sl);
    float* den = (float*)(w8 + o_den);
    float* z2  = (float*)(w8 + o_z2);
    float* cm  = (float*)(w8 + o_cm);
    f16*   Az  = (f16*)(w8 + o_az);
    f16*   Bp  = (f16*)(w8 + o_ch);
    f16*   Tt  = (f16*)(w8 + o_ch + (size_t)1536 * Mc);
    f16*   wb  = (f16*)(w8 + o_ch + (size_t)2560 * Mc);

    hipMemsetAsync(w8 + o_den, 0, 4096, stream);      // zero den only

    for (int ci = 0; ci < nch; ++ci) {
        const int m0 = ci * Mc;
        const int n0 = (ci == 0) ? 256 : 0;
        const int n1 = (ci == 0) ? Mm / 4 : 0;
        const int n2 = (96 * Mc) / 256;
        const int n3 = (Mc / 64) * (Ss / 64);
        cpsf_prep_pack<<<n0 + n1 + n2 + n3, 256, 0, stream>>>(
            z_re, z_im, d_re, d_im, zj_re, zj_im, dj_re, dj_im, T_re, T_im,
            alpha, s_par, s_perp, z2, cm, Az, Bp, Tt, Mc, m0, n0, n1, n2, mshift);
        cpsf_gemm_w<<<dim3(Mc / 64, Bq / 128), 256, 0, stream>>>(
            Az, Bp, cm, z2, wb, den, Mc, m0);
        cpsf_gemm_out<<<dim3(4, Bq / 128, zs), 256, 0, stream>>>(
            wb, Tt, osl + (size_t)ci * zs * ((size_t)Bq * 512), Mc, Kw);
    }
    cpsf_fin<<<(Bq * 512) / 256, 256, 0, stream>>>(osl, den, (float*)d_out, Z);
}

// Round 6
// 209.125 us; speedup vs baseline: 1.1191x; 1.1191x over previous
//
#include <hip/hip_runtime.h>
#include <math.h>

// Problem sizes (fixed by reference)
#define Bq 1024
#define Nn 128
#define Mm 8192
#define Ss 256

typedef _Float16 f16;
typedef _Float16 f16x8 __attribute__((ext_vector_type(8)));
typedef _Float16 f16x4 __attribute__((ext_vector_type(4)));
typedef float f32x4 __attribute__((ext_vector_type(4)));

#define PI_F 3.14159265358979323846f
#define INV_SQRT_PI 0.5641895835477563f
#define TINY_F 1.17549435e-38f
#define EPS_TOTAL 1e-3f
#define WSC 1024.0f   // w scaling so f16 w stays out of subnormals

// async global->LDS copy, 16B per lane; LDS dest = wave-uniform base + lane*16
#define GLOAD16(g, l) \
    __builtin_amdgcn_global_load_lds((const __attribute__((address_space(1))) void*)(g), \
                                     (__attribute__((address_space(3))) void*)(l), 16, 0, 0)

// ---------------- fused prep+pack: 4 block ranges ----------------
// [0,n0): b-side (|z|^2 + frag-native A pack). n0=256 on chunk 0 else 0.
// [n0,n0+n1): m-side cm constants. n1=2048 on chunk 0 else 0.
// [n0+n1, +n2): pack Bp chunk (frag-native, raw dj/zj with sign).
// [n0+n1+n2, +n3): pack Tt chunk (transposed, via LDS).
__global__ void cpsf_prep_pack(
    const float* __restrict__ z_re, const float* __restrict__ z_im,
    const float* __restrict__ d_re, const float* __restrict__ d_im,
    const float* __restrict__ zj_re, const float* __restrict__ zj_im,
    const float* __restrict__ dj_re, const float* __restrict__ dj_im,
    const float* __restrict__ T_re, const float* __restrict__ T_im,
    const float* __restrict__ alpha, const float* __restrict__ sp_,
    const float* __restrict__ sq_, float* __restrict__ z2,
    float* __restrict__ cm, f16* __restrict__ Az, f16* __restrict__ Bp,
    f16* __restrict__ Tt, int Mc, int m0g, int n0, int n1, int n2, int mshift)
{
    __shared__ float tsm[2 * 64 * 65];
    const int bx = blockIdx.x;
    const int tid = threadIdx.x;
    const int wid = tid >> 6;
    const int l = tid & 63;

    if (bx < n0) {
        // ---- b-side ----
        const int b = bx * 4 + wid;
        const int o = b * Nn;
        float dr0 = d_re[o + l], dr1 = d_re[o + l + 64];
        float di0 = d_im[o + l], di1 = d_im[o + l + 64];
        float zr0 = z_re[o + l], zr1 = z_re[o + l + 64];
        float zi0 = z_im[o + l], zi1 = z_im[o + l + 64];
        float sd = dr0*dr0 + di0*di0 + dr1*dr1 + di1*di1;
        float sz = zr0*zr0 + zi0*zi0 + zr1*zr1 + zi1*zi1;
#pragma unroll
        for (int off = 1; off < 64; off <<= 1) {
            sd += __shfl_xor(sd, off);
            sz += __shfl_xor(sz, off);
        }
        float nd = sqrtf(sd);
        nd = (nd == 0.0f) ? 1.0f : nd;
        float inv = 1.0f / nd;
        if (l == 0) z2[b] = sz;
        int map = l >> 5, c = l & 31;
        int k8 = (c & 15) * 8;
        const float* src = (map == 0) ? ((c < 16) ? z_re : z_im)
                                      : ((c < 16) ? d_re : d_im);
        float s = (map == 0) ? 1.0f : inv;
        float4 v0 = *(const float4*)(src + (size_t)b * Nn + k8);
        float4 v1 = *(const float4*)(src + (size_t)b * Nn + k8 + 4);
        f16x8 ov = {(f16)(v0.x*s), (f16)(v0.y*s), (f16)(v0.z*s), (f16)(v0.w*s),
                    (f16)(v1.x*s), (f16)(v1.y*s), (f16)(v1.z*s), (f16)(v1.w*s)};
        *(f16x8*)(Az + ((size_t)l * 1024 + b) * 8) = ov;
    } else if (bx < n0 + n1) {
        // ---- m-side constants ----
        const int m = (bx - n0) * 4 + wid;
        const int o = m * Nn;
        float dr0 = dj_re[o + l], dr1 = dj_re[o + l + 64];
        float di0 = dj_im[o + l], di1 = dj_im[o + l + 64];
        float zr0 = zj_re[o + l], zr1 = zj_re[o + l + 64];
        float zi0 = zj_im[o + l], zi1 = zj_im[o + l + 64];
        float snd = dr0*dr0 + di0*di0 + dr1*dr1 + di1*di1;
        float sc1 = dr0*zr0 + di0*zi0 + dr1*zr1 + di1*zi1;
        float sc2 = dr0*zi0 - di0*zr0 + dr1*zi1 - di1*zr1;
        float sz2 = zr0*zr0 + zi0*zi0 + zr1*zr1 + zi1*zi1;
#pragma unroll
        for (int off = 1; off < 64; off <<= 1) {
            snd += __shfl_xor(snd, off);
            sc1 += __shfl_xor(sc1, off);
            sc2 += __shfl_xor(sc2, off);
            sz2 += __shfl_xor(sz2, off);
        }
        if (l == 0) {
            float nd = sqrtf(snd);
            nd = (nd == 0.0f) ? 1.0f : nd;
            float inv = 1.0f / nd;
            cm[0*Mm + m] = inv;
            cm[1*Mm + m] = sc1 * inv;
            cm[2*Mm + m] = sc2 * inv;
            cm[3*Mm + m] = sz2;
            float sp = fmaxf(sp_[m], TINY_F);
            float sq = fmaxf(sq_[m], TINY_F);
            float sc = sqrtf(sp / PI_F);
            cm[4*Mm + m] = PI_F / sp;
            cm[5*Mm + m] = PI_F / sq;
            cm[6*Mm + m] = fmaxf(alpha[m], TINY_F) * sc * INV_SQRT_PI;
            cm[7*Mm + m] = sc;
        }
    } else if (bx < n0 + n1 + n2) {
        // ---- pack Bp (frag-native) ----
        int idx = (bx - n0 - n1) * 256 + tid;   // 96*Mc total
        int m = idx & (Mc - 1);
        int pc = idx >> mshift;                 // 0..95
        int p = pc >> 5, c = pc & 31;
        int mg = m0g + m;
        int hi = (c >= 16);
        int k8 = (c & 15) * 8;
        const float* src;
        float sgn = 1.0f;
        if (p == 0)      src = hi ? dj_im : dj_re;
        else if (p == 1) { src = hi ? dj_re : dj_im; sgn = hi ? 1.0f : -1.0f; }
        else             src = hi ? zj_im : zj_re;
        float4 v0 = *(const float4*)(src + (size_t)mg * Nn + k8);
        float4 v1 = *(const float4*)(src + (size_t)mg * Nn + k8 + 4);
        f16x8 o = {(f16)(v0.x*sgn), (f16)(v0.y*sgn), (f16)(v0.z*sgn), (f16)(v0.w*sgn),
                   (f16)(v1.x*sgn), (f16)(v1.y*sgn), (f16)(v1.z*sgn), (f16)(v1.w*sgn)};
        *(f16x8*)(Bp + (size_t)idx * 8) = o;
    } else {
        // ---- pack Tt (transposed) ----
        const int bt = bx - n0 - n1 - n2;
        const int nmb = Mc >> 6;
        const int mb = (bt & (nmb - 1)) * 64, sb = (bt / nmb) * 64;
        float* tr = tsm;
        float* ti = tsm + 64 * 65;
        const int i0 = tid >> 6, jj0 = tid & 63;
#pragma unroll
        for (int it = 0; it < 16; ++it) {
            int i = it * 4 + i0;
            tr[i * 65 + jj0] = T_re[(size_t)(m0g + mb + i) * Ss + sb + jj0];
            ti[i * 65 + jj0] = T_im[(size_t)(m0g + mb + i) * Ss + sb + jj0];
        }
        __syncthreads();
#pragma unroll
        for (int it = 0; it < 16; ++it) {
            int jj = it * 4 + i0;
            int sp = (sb + jj) * 2;
            Tt[(size_t)sp * Mc + mb + jj0]       = (f16)tr[jj0 * 65 + jj];
            Tt[(size_t)(sp + 1) * Mc + mb + jj0] = (f16)ti[jj0 * 65 + jj];
        }
    }
}

// ---------------- MFMA kernel A: LDS dbuf + counted vmcnt + raw barriers ----------------
// (round-4 proven version: 86 us) Block 128b x 64m, 4 waves (2x2), K=256 (8 steps of 32).
__global__ __launch_bounds__(256, 2) void cpsf_gemm_w(
    const f16* __restrict__ Az, const f16* __restrict__ Bp,
    const float* __restrict__ cm, const float* __restrict__ z2v,
    f16* __restrict__ wbuf, float* __restrict__ den, int Mc, int m0g)
{
    __shared__ __align__(16) f16 sm[2 * 1792 * 8];   // 56 KB
    const int tid = threadIdx.x;
    const int wid = tid >> 6;
    const int lane = tid & 63;
    const int q = lane >> 4;
    const int li = lane & 15;

    // XCD-aware swizzle: XCD x owns contiguous 1/8 of m-tiles
    const int nmt = gridDim.x;
    const int sbid = blockIdx.x + nmt * blockIdx.y;
    const int xcd = sbid & 7;
    const int jb = sbid >> 3;
    const int mpg = nmt >> 3;
    const int mtile = xcd * mpg + (jb & (mpg - 1));
    const int btile = jb / mpg;
    const int mb0 = mtile * 64;
    const int bb0 = btile * 128;
    const int wb0 = (wid >> 1) * 64;
    const int wm0 = (wid & 1) * 32;
    const int BUFO = 1792 * 8;

    // staging sources: 7 slots/thread, c = i*4+wid; frag-native layouts -> 16B/lane coalesced
    const f16* gp[7];
    size_t gstep[7];
    f16* lb[7];
#pragma unroll
    for (int i = 0; i < 7; ++i) {
        int c = i * 4 + wid;
        const f16* src;
        size_t st;
        if (c < 8) {                       // A-z chunks (LDS slots [g][b] 0..511)
            int g = c >> 1, row = (c & 1) * 64 + lane;
            src = Az + ((size_t)g * 1024 + bb0 + row) * 8;
            st = (size_t)4 * 1024 * 8;
        } else if (c < 16) {               // A-u chunks (slots 512..1023)
            int c2 = c - 8;
            int g = c2 >> 1, row = (c2 & 1) * 64 + lane;
            src = Az + ((size_t)(32 + g) * 1024 + bb0 + row) * 8;
            st = (size_t)4 * 1024 * 8;
        } else {                           // B maps (slots 1024 + g*192 + p*64 + m)
            int c2 = c - 16;
            int g = c2 / 3, p = c2 % 3;
            src = Bp + ((size_t)(p * 32 + g) * Mc + mb0 + lane) * 8;
            st = (size_t)4 * Mc * 8;
        }
        gp[i] = src; gstep[i] = st;
        lb[i] = sm + (size_t)(i * 256 + wid * 64) * 8;
    }

    f32x4 accP[4][2][3];   // maps 0..2 (pr_raw, pi_raw, z.zj)
    f32x4 accQ[4][2][2];   // maps 3..4 (ar_raw, ai_raw)
#pragma unroll
    for (int t = 0; t < 4; ++t)
#pragma unroll
        for (int u = 0; u < 2; ++u) {
#pragma unroll
            for (int p = 0; p < 3; ++p) accP[t][u][p] = (f32x4){0.f,0.f,0.f,0.f};
#pragma unroll
            for (int p = 0; p < 2; ++p) accQ[t][u][p] = (f32x4){0.f,0.f,0.f,0.f};
        }

    // prologue: stage step 0 into buf 0
#pragma unroll
    for (int i = 0; i < 7; ++i) { GLOAD16(gp[i], lb[i]); gp[i] += gstep[i]; }

#pragma unroll
    for (int ks = 0; ks < 8; ++ks) {
        const int p = ks & 1;
        if (ks > 0) {
            __builtin_amdgcn_sched_barrier(0);
            __builtin_amdgcn_s_barrier();              // C1: all done reading buf[p^1]
        }
        if (ks < 7) {
#pragma unroll
            for (int i = 0; i < 7; ++i) { GLOAD16(gp[i], lb[i] + (p ^ 1) * BUFO); gp[i] += gstep[i]; }
            asm volatile("s_waitcnt vmcnt(7)" ::: "memory");   // step-ks landed; ks+1 in flight
        } else {
            asm volatile("s_waitcnt vmcnt(0)" ::: "memory");
        }
        __builtin_amdgcn_sched_barrier(0);
        __builtin_amdgcn_s_barrier();                  // C2: buf[p] ready on all waves

        const f16* bs = sm + p * BUFO;
        f16x8 az[4], au[4], bf[3][2];
#pragma unroll
        for (int t = 0; t < 4; ++t) {
            az[t] = *(const f16x8*)(bs + (size_t)(q * 128 + wb0 + t * 16 + li) * 8);
            au[t] = *(const f16x8*)(bs + (size_t)(512 + q * 128 + wb0 + t * 16 + li) * 8);
        }
#pragma unroll
        for (int pp = 0; pp < 3; ++pp)
#pragma unroll
            for (int u = 0; u < 2; ++u)
                bf[pp][u] = *(const f16x8*)(bs + (size_t)(1024 + q * 192 + pp * 64 + wm0 + u * 16 + li) * 8);

        __builtin_amdgcn_s_setprio(1);
#pragma unroll
        for (int t = 0; t < 4; ++t)
#pragma unroll
            for (int u = 0; u < 2; ++u) {
#pragma unroll
                for (int pp = 0; pp < 3; ++pp)
                    accP[t][u][pp] = __builtin_amdgcn_mfma_f32_16x16x32_f16(az[t], bf[pp][u], accP[t][u][pp], 0, 0, 0);
#pragma unroll
                for (int pp = 0; pp < 2; ++pp)
                    accQ[t][u][pp] = __builtin_amdgcn_mfma_f32_16x16x32_f16(au[t], bf[pp][u], accQ[t][u][pp], 0, 0, 0);
            }
        __builtin_amdgcn_s_setprio(0);
    }

    // ---------------- epilogue (fp32) ----------------
    const float GT[8] = {-2.9306374202572440f, -1.9816567566958429f,
                         -1.1571937124467802f, -0.3811869902073221f,
                          0.3811869902073221f,  1.1571937124467802f,
                          1.9816567566958429f,  2.9306374202572440f};
    const float GW[8] = {1.9960407221136762e-04f, 1.7077983007413475e-02f,
                         2.0780232581489188e-01f, 6.6114701255824129e-01f,
                         6.6114701255824129e-01f, 2.0780232581489188e-01f,
                         1.7077983007413475e-02f, 1.9960407221136762e-04f};

    float iv[2], c1[2], c2[2], zj2[2], isp[2], isq[2], cf[2], scl[2];
#pragma unroll
    for (int u = 0; u < 2; ++u) {
        int mg = m0g + mb0 + wm0 + u * 16 + li;
        iv[u]  = cm[0*Mm + mg];
        c1[u]  = cm[1*Mm + mg];  c2[u]  = cm[2*Mm + mg];
        zj2[u] = cm[3*Mm + mg];  isp[u] = cm[4*Mm + mg];
        isq[u] = cm[5*Mm + mg];  cf[u]  = cm[6*Mm + mg];
        scl[u] = cm[7*Mm + mg];
    }

    float dsum[4][4];
#pragma unroll
    for (int t = 0; t < 4; ++t)
#pragma unroll
        for (int r = 0; r < 4; ++r) dsum[t][r] = 0.f;

#pragma unroll
    for (int t = 0; t < 4; ++t) {
#pragma unroll
        for (int r = 0; r < 4; ++r) {
            const int b = bb0 + wb0 + t * 16 + q * 4 + r;
            const float z2b = z2v[b];
#pragma unroll
            for (int u = 0; u < 2; ++u) {
                float pr = accP[t][u][0][r] * iv[u] - c1[u];
                float pi = accP[t][u][1][r] * iv[u] - c2[u];
                float dz2 = z2b + zj2[u] - 2.0f * accP[t][u][2][r];
                float perp2 = fmaxf(dz2 - pr * pr - pi * pi, 0.0f);
                float base = -(isq[u] * perp2 + isp[u] * pi * pi);
                float rho = 0.0f;
#pragma unroll
                for (int k = 0; k < 8; ++k) {
                    float dd = pr - scl[u] * GT[k];
                    rho = fmaf(GW[k], __expf(base - isp[u] * dd * dd), rho);
                }
                float ar = accQ[t][u][0][r] * iv[u], ai = accQ[t][u][1][r] * iv[u];
                float wv = cf[u] * (ar * ar + ai * ai) * rho;
                dsum[t][r] += wv;
                wbuf[(size_t)b * Mc + mb0 + wm0 + u * 16 + li] = (f16)(wv * WSC);
            }
        }
    }
#pragma unroll
    for (int t = 0; t < 4; ++t)
#pragma unroll
        for (int r = 0; r < 4; ++r) {
            float v = dsum[t][r];
            v += __shfl_xor(v, 1);
            v += __shfl_xor(v, 2);
            v += __shfl_xor(v, 4);
            v += __shfl_xor(v, 8);
            if (li == 0) atomicAdd(den + bb0 + wb0 + t * 16 + q * 4 + r, v);
        }
}

// ---------------- MFMA kernel B: osl[z] = w @ Tt^T (split-K slices, NO atomics) ----------------
// Flat grid 32*zs blocks, XCD-group swizzle: xcd owns all 8 b-tiles x its z-range
// -> per-XCD footprint (wbuf ~2MB + Tt ~1MB) fits 4MB L2.
// K-step = 64 (8 steps at Kw=512): LDS 64KB dbuf, counted vmcnt(8), raw barriers.
__global__ __launch_bounds__(256, 2) void cpsf_gemm_out(
    const f16* __restrict__ wbuf, const f16* __restrict__ Tt,
    float* __restrict__ osl, int Mc, int Kw, int zs)
{
    __shared__ __align__(16) f16 sm[2 * 2048 * 8];   // 64 KB
    const int tid = threadIdx.x;
    const int wid = tid >> 6;
    const int lane = tid & 63;
    const int q = lane >> 4;
    const int li = lane & 15;

    // XCD-group decode: bid = blockIdx.x in [0, 32*zs)
    const int bid = blockIdx.x;
    const int xcd = bid & 7;
    const int j = bid >> 3;              // 0 .. 4*zs-1
    const int s = j / zs;                // 0..3  s'-block
    const int g = xcd * zs + (j % zs);   // group in [0, 8*zs)
    const int zb = g >> 3;               // z-slice
    const int yb = g & 7;                // b-tile
    const int sb0 = s * 128;
    const int bb0 = yb * 128;
    const int kz0 = zb * Kw;
    float* oz = osl + (size_t)zb * ((size_t)Bq * 512);
    const int wb0 = (wid >> 1) * 64;
    const int ws0 = (wid & 1) * 64;
    const int BUFO = 2048 * 8;

    // staging: 32 slot-groups of 64 (w: c<16, Tt: c>=16); 8 issues/thread/step
    const f16* gp[8];
    f16* lb[8];
#pragma unroll
    for (int i = 0; i < 8; ++i) {
        int c = i * 4 + wid;             // 0..31
        const f16* src;
        if (c < 16) {
            int gch = c >> 1, row = (c & 1) * 64 + lane;
            src = wbuf + (size_t)(bb0 + row) * Mc + kz0 + gch * 8;
        } else {
            int c2 = c - 16;
            int gch = c2 >> 1, row = (c2 & 1) * 64 + lane;
            src = Tt + (size_t)(sb0 + row) * Mc + kz0 + gch * 8;
        }
        gp[i] = src;
        lb[i] = sm + (size_t)(c * 64) * 8;
    }

    f32x4 acc[4][4];
#pragma unroll
    for (int t = 0; t < 4; ++t)
#pragma unroll
        for (int u = 0; u < 4; ++u) acc[t][u] = (f32x4){0.f,0.f,0.f,0.f};

    // prologue: stage step 0 (64 k)
#pragma unroll
    for (int i = 0; i < 8; ++i) { GLOAD16(gp[i], lb[i]); gp[i] += 64; }

    const int nk = Kw >> 6;              // steps of 64 k
    for (int kc = 0; kc < nk; ++kc) {
        const int p = kc & 1;
        if (kc > 0) {
            __builtin_amdgcn_sched_barrier(0);
            __builtin_amdgcn_s_barrier();
        }
        if (kc + 1 < nk) {
#pragma unroll
            for (int i = 0; i < 8; ++i) { GLOAD16(gp[i], lb[i] + (p ^ 1) * BUFO); gp[i] += 64; }
            asm volatile("s_waitcnt vmcnt(8)" ::: "memory");
        } else {
            asm volatile("s_waitcnt vmcnt(0)" ::: "memory");
        }
        __builtin_amdgcn_sched_barrier(0);
        __builtin_amdgcn_s_barrier();

        const f16* bs = sm + p * BUFO;
#pragma unroll
        for (int kk = 0; kk < 2; ++kk) {
            f16x8 af[4], bf[4];
#pragma unroll
            for (int t = 0; t < 4; ++t)
                af[t] = *(const f16x8*)(bs + (size_t)((kk * 4 + q) * 128 + wb0 + t * 16 + li) * 8);
#pragma unroll
            for (int u = 0; u < 4; ++u)
                bf[u] = *(const f16x8*)(bs + (size_t)(1024 + (kk * 4 + q) * 128 + ws0 + u * 16 + li) * 8);
            __builtin_amdgcn_s_setprio(1);
#pragma unroll
            for (int t = 0; t < 4; ++t)
#pragma unroll
                for (int u = 0; u < 4; ++u)
                    acc[t][u] = __builtin_amdgcn_mfma_f32_16x16x32_f16(af[t], bf[u], acc[t][u], 0, 0, 0);
            __builtin_amdgcn_s_setprio(0);
        }
    }
#pragma unroll
    for (int t = 0; t < 4; ++t)
#pragma unroll
        for (int u = 0; u < 4; ++u)
#pragma unroll
            for (int r = 0; r < 4; ++r)
                oz[(size_t)(bb0 + wb0 + t * 16 + q * 4 + r) * 512 + sb0 + ws0 + u * 16 + li] =
                    acc[t][u][r];
}

// ---------------- finalize: sum Z slices (float4), divide ----------------
__global__ void cpsf_fin(const float* __restrict__ osl, const float* __restrict__ den,
                         float* __restrict__ out, int Z)
{
    int i = (blockIdx.x * 256 + threadIdx.x) * 4;
    float4 s = {0.f, 0.f, 0.f, 0.f};
    for (int z = 0; z < Z; ++z) {
        float4 v = *(const float4*)(osl + (size_t)z * ((size_t)Bq * 512) + i);
        s.x += v.x; s.y += v.y; s.z += v.z; s.w += v.w;
    }
    float d = 1.0f / ((den[i >> 9] + EPS_TOTAL) * WSC);
    float4 o = {s.x * d, s.y * d, s.z * d, s.w * d};
    *(float4*)(out + i) = o;
}

extern "C" void kernel_launch(void* const* d_in, const int* in_sizes, int n_in,
                              void* d_out, int out_size, void* d_ws, size_t ws_size,
                              hipStream_t stream)
{
    (void)in_sizes; (void)n_in; (void)out_size;
    const float* z_re  = (const float*)d_in[0];
    const float* z_im  = (const float*)d_in[1];
    const float* d_re  = (const float*)d_in[2];
    const float* d_im  = (const float*)d_in[3];
    const float* zj_re = (const float*)d_in[4];
    const float* zj_im = (const float*)d_in[5];
    const float* dj_re = (const float*)d_in[6];
    const float* dj_im = (const float*)d_in[7];
    const float* T_re  = (const float*)d_in[8];
    const float* T_im  = (const float*)d_in[9];
    const float* alpha = (const float*)d_in[10];
    const float* s_par = (const float*)d_in[11];
    const float* s_perp= (const float*)d_in[12];

    const size_t SL = (size_t)Bq * 512 * 4;           // 2 MB per slice
    const size_t fixedA = 4096 + 4096 + (size_t)8 * Mm * 4 + (size_t)Bq * 512 * 2;

    // choose total split-K slices Z and chunk size Mc (prefer parallelism, then chunk size)
    int Mc = 0, Z = 0;
    const int Zopt[3] = {16, 8, 4};
    const int Mopt[4] = {8192, 4096, 2048, 1024};
    for (int zi = 0; zi < 3 && !Mc; ++zi)
        for (int mi = 0; mi < 4; ++mi) {
            int Zc = Zopt[zi], Mcc = Mopt[mi];
            int nch = Mm / Mcc;
            if (Zc % nch) continue;
            if (Mcc / (Zc / nch) < 64) continue;      // Kw >= 64
            size_t need = (size_t)Zc * SL + fixedA + (size_t)4608 * Mcc;
            if (need <= ws_size) { Mc = Mcc; Z = Zc; break; }
        }
    if (!Mc) { Mc = 1024; Z = 8; }
    const int nch = Mm / Mc;
    const int zs = Z / nch;
    const int Kw = Mc / zs;
    const int mshift = 31 - __builtin_clz((unsigned)Mc);

    char* w8 = (char*)d_ws;
    const size_t o_sl  = 0;
    const size_t o_den = o_sl + (size_t)Z * SL;
    const size_t o_z2  = o_den + 4096;
    const size_t o_cm  = o_z2 + 4096;
    const size_t o_az  = o_cm + (size_t)8 * Mm * 4;
    const size_t o_ch  = o_az + (size_t)Bq * 512 * 2;

    float* osl = (float*)(w8 + o_sl);
    float* den = (float*)(w8 + o_den);
    float* z2  = (float*)(w8 + o_z2);
    float* cm  = (float*)(w8 + o_cm);
    f16*   Az  = (f16*)(w8 + o_az);
    f16*   Bp  = (f16*)(w8 + o_ch);
    f16*   Tt  = (f16*)(w8 + o_ch + (size_t)1536 * Mc);
    f16*   wb  = (f16*)(w8 + o_ch + (size_t)2560 * Mc);

    hipMemsetAsync(w8 + o_den, 0, 4096, stream);      // zero den only

    for (int ci = 0; ci < nch; ++ci) {
        const int m0 = ci * Mc;
        const int n0 = (ci == 0) ? 256 : 0;
        const int n1 = (ci == 0) ? Mm / 4 : 0;
        const int n2 = (96 * Mc) / 256;
        const int n3 = (Mc / 64) * (Ss / 64);
        cpsf_prep_pack<<<n0 + n1 + n2 + n3, 256, 0, stream>>>(
            z_re, z_im, d_re, d_im, zj_re, zj_im, dj_re, dj_im, T_re, T_im,
            alpha, s_par, s_perp, z2, cm, Az, Bp, Tt, Mc, m0, n0, n1, n2, mshift);
        cpsf_gemm_w<<<dim3(Mc / 64, Bq / 128), 256, 0, stream>>>(
            Az, Bp, cm, z2, wb, den, Mc, m0);
        cpsf_gemm_out<<<32 * zs, 256, 0, stream>>>(
            wb, Tt, osl + (size_t)ci * zs * ((size_t)Bq * 512), Mc, Kw, zs);
    }
    cpsf_fin<<<(Bq * 512) / 1024, 256, 0, stream>>>(osl, den, (float*)d_out, Z);
}